// Round 16
// baseline (320.776 us; speedup 1.0000x reference)
//
#include <hip/hip_runtime.h>

typedef __attribute__((ext_vector_type(4))) float f32x4;
typedef __attribute__((ext_vector_type(8))) __bf16 bf16x8;
typedef __attribute__((ext_vector_type(8))) unsigned short ushort8;

static __device__ __forceinline__ unsigned short f2bf(float f) {
    unsigned int u = __float_as_uint(f);
    u += 0x7fffu + ((u >> 16) & 1u);   // round-to-nearest-even
    return (unsigned short)(u >> 16);
}
static __device__ __forceinline__ float bf2f(unsigned short u) {
    return __uint_as_float((unsigned int)u << 16);
}
static __device__ __forceinline__ bf16x8 as_bf(ushort8 v) {
    union { ushort8 u; bf16x8 b; } x; x.u = v; return x.b;
}
// async global->LDS, 16B per lane. LDS dest = wave-uniform base + lane*16.
static __device__ __forceinline__ void gll16(const void* g, void* l) {
    __builtin_amdgcn_global_load_lds(
        (const __attribute__((address_space(1))) void*)g,
        (__attribute__((address_space(3))) void*)l, 16, 0, 0);
}

// ---------------------------------------------------------------------------
// f32 -> bf16 convert (8 elems/thread)
// ---------------------------------------------------------------------------
__global__ void cvt_bf16(const float* __restrict__ in, unsigned short* __restrict__ out,
                         int n8) {
    int i = blockIdx.x * 256 + threadIdx.x;
    if (i >= n8) return;
    const float4* p = (const float4*)(in + (size_t)i * 8);
    float4 a = p[0], b = p[1];
    ushort8 o = { f2bf(a.x), f2bf(a.y), f2bf(a.z), f2bf(a.w),
                  f2bf(b.x), f2bf(b.y), f2bf(b.z), f2bf(b.w) };
    *(ushort8*)(out + (size_t)i * 8) = o;
}

// ---------------------------------------------------------------------------
// transpose + convert: in [K][N] f32 -> out [N][K] bf16. 64x64 tiles.
// ---------------------------------------------------------------------------
__global__ void tconv_bf16(const float* __restrict__ in, unsigned short* __restrict__ out,
                           int K, int N) {
    __shared__ float t[64][65];
    const int tid = threadIdx.x;
    const int n0 = blockIdx.x * 64, k0 = blockIdx.y * 64;
#pragma unroll
    for (int i = 0; i < 4; i++) {
        int idx = tid + 256 * i;
        int r = idx >> 4, c4 = (idx & 15) * 4;
        float4 v = *(const float4*)(in + (size_t)(k0 + r) * N + n0 + c4);
        t[r][c4] = v.x; t[r][c4 + 1] = v.y; t[r][c4 + 2] = v.z; t[r][c4 + 3] = v.w;
    }
    __syncthreads();
#pragma unroll
    for (int i = 0; i < 2; i++) {
        int idx = tid + 256 * i;
        int nl = idx >> 3, k8 = (idx & 7) * 8;
        ushort8 o;
#pragma unroll
        for (int j = 0; j < 8; j++) o[j] = f2bf(t[k8 + j][nl]);
        *(ushort8*)(out + (size_t)(n0 + nl) * K + k0 + k8) = o;
    }
}

// ---------------------------------------------------------------------------
// GEMM1: 256x256 tile, BK=32, 8 waves, counted-vmcnt pipeline (r11, verified).
// ---------------------------------------------------------------------------
__global__ __launch_bounds__(512, 2)
void gemm256_qkv(const unsigned short* __restrict__ A,
                 const unsigned short* __restrict__ BT,
                 const float* __restrict__ bias,
                 unsigned short* __restrict__ qh, unsigned short* __restrict__ kh,
                 unsigned short* __restrict__ vt, int K)
{
    __shared__ char smem[65536];
    const int tid = threadIdx.x;
    const int wid = tid >> 6, lane = tid & 63;
    const int g = lane >> 4, c = lane & 15;
    const int wr = (wid >> 2) * 128;      // M-wave row base (0 / 128)
    const int wc = (wid & 3) * 64;        // N-wave col base (0..192)

    const int nwg = gridDim.x;            // 384 (div by 8)
    const int swz = ((int)blockIdx.x & 7) * (nwg >> 3) + ((int)blockIdx.x >> 3);
    const int bm = (swz & 31) * 256;      // 32 m-tiles
    const int bn = (swz >> 5) * 256;      // 12 n-tiles

    const int sch   = (lane & 7) ^ (lane >> 3);          // swizzled chunk 0..7
    const int srow2 = ((lane >> 3) << 1) + (sch >> 2);   // row offset in 16-row slab
    const int scol  = (sch & 3) * 8;                     // col elems (8 bf16)
    const int fbase = (c >> 1) * 128 + (((((c & 1) << 2) | g) ^ (c >> 1)) * 16);

    f32x4 acc[8][4] = {};

    auto stage = [&](int p, int kt) {
        const int k0 = kt * 32;
        char* bufA = smem + p * 32768;
        char* bufB = bufA + 16384;
#pragma unroll
        for (int half = 0; half < 2; half++) {
            const int PRb = half * 64;
            const int rbase = PRb * 2 + wid * 16 + srow2;
            gll16(A + (size_t)(bm + rbase) * K + k0 + scol,
                  bufA + (PRb + wid * 8) * 128);
            gll16(BT + (size_t)(bn + rbase) * K + k0 + scol,
                  bufB + (PRb + wid * 8) * 128);
        }
    };

    const int NT = K >> 5;    // 32 K-tiles of 32
    stage(0, 0);
    stage(1, 1);

    for (int kt = 0; kt < NT - 1; ++kt) {
        asm volatile("s_waitcnt vmcnt(4)" ::: "memory");   // kt landed; kt+1 in flight
        __builtin_amdgcn_s_barrier();
        const char* bufA = smem + (kt & 1) * 32768;
        const char* bufB = bufA + 16384;
        bf16x8 af[8], bf[4];
#pragma unroll
        for (int mi = 0; mi < 8; mi++)
            af[mi] = as_bf(*(const ushort8*)(bufA + wr * 64 + mi * 1024 + fbase));
#pragma unroll
        for (int ni = 0; ni < 4; ni++)
            bf[ni] = as_bf(*(const ushort8*)(bufB + wc * 64 + ni * 1024 + fbase));
        asm volatile("s_waitcnt lgkmcnt(0)" ::: "memory");
        __builtin_amdgcn_sched_barrier(0);
        __builtin_amdgcn_s_barrier();      // all waves done reading buf[kt&1]
        if (kt + 2 < NT) stage(kt & 1, kt + 2);
        __builtin_amdgcn_sched_barrier(0); // keep stage issue ahead of MFMA
        __builtin_amdgcn_s_setprio(1);
#pragma unroll
        for (int mi = 0; mi < 8; mi++)
#pragma unroll
            for (int ni = 0; ni < 4; ni++)
                acc[mi][ni] = __builtin_amdgcn_mfma_f32_16x16x32_bf16(
                    af[mi], bf[ni], acc[mi][ni], 0, 0, 0);
        __builtin_amdgcn_s_setprio(0);
    }
    {   // final K-tile
        asm volatile("s_waitcnt vmcnt(0)" ::: "memory");
        __builtin_amdgcn_s_barrier();
        const char* bufA = smem + ((NT - 1) & 1) * 32768;
        const char* bufB = bufA + 16384;
        bf16x8 af[8], bf[4];
#pragma unroll
        for (int mi = 0; mi < 8; mi++)
            af[mi] = as_bf(*(const ushort8*)(bufA + wr * 64 + mi * 1024 + fbase));
#pragma unroll
        for (int ni = 0; ni < 4; ni++)
            bf[ni] = as_bf(*(const ushort8*)(bufB + wc * 64 + ni * 1024 + fbase));
        asm volatile("s_waitcnt lgkmcnt(0)" ::: "memory");
        __builtin_amdgcn_sched_barrier(0);
        __builtin_amdgcn_s_barrier();      // frags in regs; LDS free for epilogue
#pragma unroll
        for (int mi = 0; mi < 8; mi++)
#pragma unroll
            for (int ni = 0; ni < 4; ni++)
                acc[mi][ni] = __builtin_amdgcn_mfma_f32_16x16x32_bf16(
                    af[mi], bf[ni], acc[mi][ni], 0, 0, 0);
    }

    // ---- per-wave epilogue ----
    const int n0 = bn + wc;
    const int region = n0 >> 10;
    const int h = (n0 & 1023) >> 6;
    const int b = bm >> 10;
    const int lb = bm & 1023;             // LOCAL sequence base
    const float qscale = (region == 0) ? 0.1803368801f : 1.0f;  // 0.125*log2(e)
    char* W = smem + wid * 8192;   // private 8KB slice per wave

    if (region < 2) {
        unsigned short* dst = (region == 0) ? qh : kh;
#pragma unroll
        for (int hh = 0; hh < 2; hh++) {
#pragma unroll
            for (int mi2 = 0; mi2 < 4; mi2++) {
                int mi = hh * 4 + mi2;
#pragma unroll
                for (int ni = 0; ni < 4; ni++)
#pragma unroll
                    for (int r = 0; r < 4; r++) {
                        int row = mi2 * 16 + g * 4 + r;        // 0..63
                        int col = ni * 16 + c;
                        float v = (acc[mi][ni][r] + bias[n0 + col]) * qscale;
                        *(unsigned short*)(W + row * 128 + ((col * 2) ^ ((row & 7) << 4))) = f2bf(v);
                    }
            }
#pragma unroll
            for (int j = 0; j < 8; j++) {
                int cid = j * 64 + lane;
                int row = cid >> 3, c8 = cid & 7;
                ushort8 v = *(const ushort8*)(W + row * 128 + ((c8 * 16) ^ ((row & 7) << 4)));
                int l = lb + wr + hh * 64 + row;
                *(ushort8*)(dst + ((size_t)((b * 16 + h) * 1024 + l)) * 64 + c8 * 8) = v;
            }
        }
    } else {
#pragma unroll
        for (int hh = 0; hh < 2; hh++) {
#pragma unroll
            for (int mi2 = 0; mi2 < 4; mi2++) {
                int mi = hh * 4 + mi2;
#pragma unroll
                for (int ni = 0; ni < 4; ni++)
#pragma unroll
                    for (int r = 0; r < 4; r++) {
                        int ll = mi2 * 16 + g * 4 + r;         // local l 0..63
                        int d = ni * 16 + c;
                        float v = acc[mi][ni][r] + bias[n0 + d];
                        *(unsigned short*)(W + d * 128 + ((ll * 2) ^ ((d & 7) << 4))) = f2bf(v);
                    }
            }
#pragma unroll
            for (int j = 0; j < 8; j++) {
                int cid = j * 64 + lane;
                int drow = cid >> 3, c8 = cid & 7;
                ushort8 v = *(const ushort8*)(W + drow * 128 + ((c8 * 16) ^ ((drow & 7) << 4)));
                *(ushort8*)(vt + ((size_t)((b * 16 + h) * 64 + drow)) * 1024
                            + (lb + wr + hh * 64) + c8 * 8) = v;
            }
        }
    }
}

// ---------------------------------------------------------------------------
// GEMM2 fused: s[m][n] = bf16( A@W^T + bias + x )  (residual folded in)
// ---------------------------------------------------------------------------
__global__ __launch_bounds__(256, 2)
void gemm128_res(const unsigned short* __restrict__ A,
                 const unsigned short* __restrict__ BT,
                 const float* __restrict__ bias,
                 const float* __restrict__ x,
                 unsigned short* __restrict__ sb, int K, int mtiles, int Ncols)
{
    __shared__ unsigned short smem[2 * 128 * 64];
    unsigned short* As = smem;
    unsigned short* Bs = smem + 128 * 64;

    const int tid = threadIdx.x;
    const int wid = tid >> 6, lane = tid & 63;
    const int g = lane >> 4, c = lane & 15;
    const int wr = (wid >> 1) * 64, wc = (wid & 1) * 64;

    const int nwg = gridDim.x;
    const int swz = ((int)blockIdx.x & 7) * (nwg >> 3) + ((int)blockIdx.x >> 3);
    const int bm = (swz % mtiles) * 128;
    const int bn = (swz / mtiles) * 128;

    const int srow = lane >> 3;
    const int scol8 = ((lane & 7) ^ srow) * 8;
    const size_t arow0 = (size_t)(bm + wid * 8 + srow);
    const size_t brow0 = (size_t)(bn + wid * 8 + srow);

    f32x4 acc[4][4] = {};

    for (int k0 = 0; k0 < K; k0 += 64) {
        __syncthreads();
#pragma unroll
        for (int t = 0; t < 4; t++) {
            gll16(A + (arow0 + t * 32) * K + k0 + scol8,
                  (char*)As + t * 4096 + wid * 1024);
            gll16(BT + (brow0 + t * 32) * K + k0 + scol8,
                  (char*)Bs + t * 4096 + wid * 1024);
        }
        __syncthreads();
#pragma unroll
        for (int ks = 0; ks < 2; ks++) {
            bf16x8 af[4], bfr[4];
#pragma unroll
            for (int mi = 0; mi < 4; mi++) {
                int row = wr + mi * 16 + c;
                int off = row * 128 + ((ks * 64 + g * 16) ^ ((c & 7) << 4));
                af[mi] = as_bf(*(const ushort8*)((const char*)As + off));
            }
#pragma unroll
            for (int ni = 0; ni < 4; ni++) {
                int row = wc + ni * 16 + c;
                int off = row * 128 + ((ks * 64 + g * 16) ^ ((c & 7) << 4));
                bfr[ni] = as_bf(*(const ushort8*)((const char*)Bs + off));
            }
#pragma unroll
            for (int mi = 0; mi < 4; mi++)
#pragma unroll
                for (int ni = 0; ni < 4; ni++)
                    acc[mi][ni] = __builtin_amdgcn_mfma_f32_16x16x32_bf16(
                        af[mi], bfr[ni], acc[mi][ni], 0, 0, 0);
        }
    }

#pragma unroll
    for (int mi = 0; mi < 4; mi++)
#pragma unroll
        for (int ni = 0; ni < 4; ni++)
#pragma unroll
            for (int r = 0; r < 4; r++) {
                int m = bm + wr + mi * 16 + g * 4 + r;
                int n = bn + wc + ni * 16 + c;
                float v = acc[mi][ni][r] + bias[n] + x[(size_t)m * Ncols + n];
                sb[(size_t)m * Ncols + n] = f2bf(v);
            }
}

// ---------------------------------------------------------------------------
// Attention (r14 version: LJF dispatch). CHANGE: all attn f32 stores are
// NONTEMPORAL (attn is write-once/never-read -> bypass L2 write-allocate,
// keep L2 for the K/V re-read working set).
// ---------------------------------------------------------------------------
__global__ __launch_bounds__(256, 3)
void attn_kernel(const unsigned short* __restrict__ qh,
                 const unsigned short* __restrict__ kh,
                 const unsigned short* __restrict__ vt,
                 float* __restrict__ attn, unsigned short* __restrict__ ob)
{
    __shared__ char smem[49152];

    const int bh = blockIdx.x;       // b*16 + h
    const int qt = 15 - (int)blockIdx.y;   // LJF: big tiles dispatch first
    const int q0 = qt * 64;
    const int ntiles = qt + 1;

    const int tid = threadIdx.x, wid = tid >> 6, lane = tid & 63;
    const int g = lane >> 4, c = lane & 15;

    const size_t baseKV = (size_t)bh * 65536;
    const int qrow = q0 + wid * 16 + c;

    bf16x8 qa[2];
    qa[0] = as_bf(*(const ushort8*)(qh + baseKV + (size_t)qrow * 64 + g * 8));
    qa[1] = as_bf(*(const ushort8*)(qh + baseKV + (size_t)qrow * 64 + 32 + g * 8));

    const int srow = lane >> 3;
    const int scol8 = ((lane & 7) ^ srow) * 8;

    // ---- pass 1: lsum only. stage(kt+1) || compute(kt), 1 barrier/tile.
    float lsum = 0.f;
    {
        int cur = 0;
        const unsigned short* kb0 = kh + baseKV;
        gll16(kb0 + (size_t)(wid * 8 + srow) * 64 + scol8, smem + wid * 1024);
        gll16(kb0 + (size_t)(32 + wid * 8 + srow) * 64 + scol8, smem + 4096 + wid * 1024);
        __syncthreads();
        for (int kt = 0; kt < ntiles; ++kt) {
            if (kt + 1 < ntiles) {
                const unsigned short* kb = kh + baseKV + (size_t)(kt + 1) * 4096;
                char* dst = smem + (cur ^ 1) * 8192;
                gll16(kb + (size_t)(wid * 8 + srow) * 64 + scol8, dst + wid * 1024);
                gll16(kb + (size_t)(32 + wid * 8 + srow) * 64 + scol8, dst + 4096 + wid * 1024);
            }
            const char* Kc = smem + cur * 8192;
            __builtin_amdgcn_s_setprio(1);
#pragma unroll
            for (int a = 0; a < 4; a++) {
                int krow = a * 16 + c;
                f32x4 sa = {0.f, 0.f, 0.f, 0.f};
#pragma unroll
                for (int ks = 0; ks < 2; ks++) {
                    int off = krow * 128 + ((ks * 64 + g * 16) ^ ((c & 7) << 4));
                    bf16x8 kf = as_bf(*(const ushort8*)(Kc + off));
                    sa = __builtin_amdgcn_mfma_f32_16x16x32_bf16(kf, qa[ks], sa, 0, 0, 0);
                }
                int kb4 = kt * 64 + a * 16 + g * 4;
#pragma unroll
                for (int r = 0; r < 4; r++)
                    lsum += (kb4 + r > qrow) ? 0.f : __builtin_amdgcn_exp2f(sa[r]);
            }
            __builtin_amdgcn_s_setprio(0);
            __syncthreads();
            cur ^= 1;
        }
    }
    lsum += __shfl_xor(lsum, 16);
    lsum += __shfl_xor(lsum, 32);
    const float lr = -__log2f(lsum);

    // ---- pass 2: P (normalized at exponent), attn store (NT), O accumulate.
    float* attnB = attn + (size_t)bh * (1024 * 1024) + (size_t)q0 * 1024;
    f32x4 oacc[4] = {};
    {
        int cur = 0;
        const unsigned short* kb0 = kh + baseKV;
        const unsigned short* vb0 = vt + baseKV;
        gll16(kb0 + (size_t)(wid * 8 + srow) * 64 + scol8, smem + wid * 1024);
        gll16(kb0 + (size_t)(32 + wid * 8 + srow) * 64 + scol8, smem + 4096 + wid * 1024);
        gll16(vb0 + (size_t)(wid * 8 + srow) * 1024 + scol8, smem + 16384 + wid * 1024);
        gll16(vb0 + (size_t)(32 + wid * 8 + srow) * 1024 + scol8, smem + 20480 + wid * 1024);
        __syncthreads();

        for (int kt = 0; kt < ntiles; ++kt) {
            if (kt + 1 < ntiles) {
                const unsigned short* kb = kh + baseKV + (size_t)(kt + 1) * 4096;
                const unsigned short* vb = vt + baseKV + (kt + 1) * 64;
                char* kdst = smem + (cur ^ 1) * 8192;
                char* vdst = smem + 16384 + (cur ^ 1) * 8192;
                gll16(kb + (size_t)(wid * 8 + srow) * 64 + scol8, kdst + wid * 1024);
                gll16(kb + (size_t)(32 + wid * 8 + srow) * 64 + scol8, kdst + 4096 + wid * 1024);
                gll16(vb + (size_t)(wid * 8 + srow) * 1024 + scol8, vdst + wid * 1024);
                gll16(vb + (size_t)(32 + wid * 8 + srow) * 1024 + scol8, vdst + 4096 + wid * 1024);
            }
            const char* Kc = smem + cur * 8192;
            const char* Vc = smem + 16384 + cur * 8192;
            char* Pc = smem + 32768 + cur * 8192;
            char* Pw = Pc + wid * 2048;

#pragma unroll
            for (int a = 0; a < 4; a++) {
                int krow = a * 16 + c;
                f32x4 sa = {0.f, 0.f, 0.f, 0.f};
#pragma unroll
                for (int ks = 0; ks < 2; ks++) {
                    int off = krow * 128 + ((ks * 64 + g * 16) ^ ((c & 7) << 4));
                    bf16x8 kf = as_bf(*(const ushort8*)(Kc + off));
                    sa = __builtin_amdgcn_mfma_f32_16x16x32_bf16(kf, qa[ks], sa, 0, 0, 0);
                }
                int kb4 = kt * 64 + a * 16 + g * 4;
                float p0 = __builtin_amdgcn_exp2f((kb4 + 0 > qrow) ? -1e9f : sa[0] + lr);
                float p1 = __builtin_amdgcn_exp2f((kb4 + 1 > qrow) ? -1e9f : sa[1] + lr);
                float p2 = __builtin_amdgcn_exp2f((kb4 + 2 > qrow) ? -1e9f : sa[2] + lr);
                float p3 = __builtin_amdgcn_exp2f((kb4 + 3 > qrow) ? -1e9f : sa[3] + lr);
                uint2 pw;
                asm("v_cvt_pk_bf16_f32 %0, %1, %2" : "=v"(pw.x) : "v"(p0), "v"(p1));
                asm("v_cvt_pk_bf16_f32 %0, %1, %2" : "=v"(pw.y) : "v"(p2), "v"(p3));
                *(uint2*)(Pw + c * 128 + ((a * 32 + g * 8) ^ ((c & 7) << 4))) = pw;
            }

            __builtin_amdgcn_s_setprio(1);
#pragma unroll
            for (int ks = 0; ks < 2; ks++) {
                int aoff = c * 128 + ((ks * 64 + g * 16) ^ ((c & 7) << 4));
                bf16x8 pa = as_bf(*(const ushort8*)(Pw + aoff));
#pragma unroll
                for (int ni = 0; ni < 4; ni++) {
                    int d = ni * 16 + c;
                    int voff = d * 128 + ((ks * 64 + g * 16) ^ ((d & 7) << 4));
                    bf16x8 vf = as_bf(*(const ushort8*)(Vc + voff));
                    oacc[ni] = __builtin_amdgcn_mfma_f32_16x16x32_bf16(pa, vf, oacc[ni], 0, 0, 0);
                }
            }
            __builtin_amdgcn_s_setprio(0);
            __syncthreads();

            // attn store tile kt — NONTEMPORAL (write-once stream)
#pragma unroll
            for (int i = 0; i < 2; i++) {
                int idx = tid + 256 * i;
                int row = idx >> 3, c16 = idx & 7;
                int off = (row >> 4) * 2048 + (row & 15) * 128 + ((c16 * 16) ^ ((row & 7) << 4));
                ushort8 v = *(const ushort8*)(Pc + off);
                f32x4 f0 = { bf2f(v[0]), bf2f(v[1]), bf2f(v[2]), bf2f(v[3]) };
                f32x4 f1 = { bf2f(v[4]), bf2f(v[5]), bf2f(v[6]), bf2f(v[7]) };
                float* dp = attnB + (size_t)row * 1024 + kt * 64 + c16 * 8;
                __builtin_nontemporal_store(f0, (f32x4*)dp);
                __builtin_nontemporal_store(f1, (f32x4*)(dp + 4));
            }
            cur ^= 1;
        }
    }

    // zero the strictly-upper k-tiles — NONTEMPORAL end burst
    {
        f32x4 z = {0.f, 0.f, 0.f, 0.f};
        for (int kt = ntiles; kt < 16; ++kt) {
#pragma unroll
            for (int i = 0; i < 4; i++) {
                int idx = tid + 256 * i;
                int row = idx >> 4, c4 = (idx & 15) << 2;
                __builtin_nontemporal_store(z, (f32x4*)(attnB + (size_t)row * 1024 + kt * 64 + c4));
            }
        }
    }

    // O store via LDS roundtrip -> bf16 (re-read by GEMM2 -> keep cacheable)
    __syncthreads();
#pragma unroll
    for (int ni = 0; ni < 4; ni++)
#pragma unroll
        for (int r = 0; r < 4; r++) {
            int row = wid * 16 + g * 4 + r;
            int d = ni * 16 + c;
            int off = row * 128 + ((d * 2) ^ ((row & 7) << 4));
            *(unsigned short*)(smem + off) = f2bf(oacc[ni][r]);
        }
    __syncthreads();
    {
        const int b = bh >> 4, h = bh & 15;
#pragma unroll
        for (int i = 0; i < 2; i++) {
            int idx = tid + 256 * i;
            int row = idx >> 3, c8 = idx & 7;
            int off = row * 128 + ((c8 * 16) ^ ((row & 7) << 4));
            ushort8 v = *(const ushort8*)(smem + off);
            *(ushort8*)(ob + ((size_t)(b * 1024 + q0 + row)) * 1024 + h * 64 + c8 * 8) = v;
        }
    }
}

// ---------------------------------------------------------------------------
// LayerNorm(s) -> out   (s = y + x already fused, bf16)
// ---------------------------------------------------------------------------
__global__ __launch_bounds__(256, 2)
void ln_kernel(const unsigned short* __restrict__ sb,
               const float* __restrict__ gamma, const float* __restrict__ beta,
               float* __restrict__ out)
{
    const int m = blockIdx.x;
    const int tid = threadIdx.x;
    const int wid = tid >> 6, lane = tid & 63;
    ushort4 u = *(const ushort4*)(sb + (size_t)m * 1024 + tid * 4);
    float4 v = { bf2f(u.x), bf2f(u.y), bf2f(u.z), bf2f(u.w) };
    float s1 = v.x + v.y + v.z + v.w;
    float s2 = v.x * v.x + v.y * v.y + v.z * v.z + v.w * v.w;
#pragma unroll
    for (int d = 1; d < 64; d <<= 1) {
        s1 += __shfl_xor(s1, d);
        s2 += __shfl_xor(s2, d);
    }
    __shared__ float red1[4], red2[4];
    if (lane == 0) { red1[wid] = s1; red2[wid] = s2; }
    __syncthreads();
    float t1 = red1[0] + red1[1] + red1[2] + red1[3];
    float t2 = red2[0] + red2[1] + red2[2] + red2[3];
    float mean = t1 * (1.f / 1024.f);
    float var = t2 * (1.f / 1024.f) - mean * mean;
    float rstd = rsqrtf(var + 1e-5f);
    float4 g4 = *(const float4*)(gamma + tid * 4);
    float4 b4 = *(const float4*)(beta + tid * 4);
    float4 o;
    o.x = g4.x * (v.x - mean) * rstd + b4.x;
    o.y = g4.y * (v.y - mean) * rstd + b4.y;
    o.z = g4.z * (v.z - mean) * rstd + b4.z;
    o.w = g4.w * (v.w - mean) * rstd + b4.w;
    *(float4*)(out + (size_t)m * 1024 + tid * 4) = o;
}

// ---------------------------------------------------------------------------
extern "C" void kernel_launch(void* const* d_in, const int* in_sizes, int n_in,
                              void* d_out, int out_size, void* d_ws, size_t ws_size,
                              hipStream_t stream)
{
    const float* x      = (const float*)d_in[0];
    // d_in[1] = mask — causal, implemented analytically
    const float* W_qkv  = (const float*)d_in[2];
    const float* b_qkv  = (const float*)d_in[3];
    const float* W_proj = (const float*)d_in[4];
    const float* b_proj = (const float*)d_in[5];
    const float* gamma  = (const float*)d_in[6];
    const float* beta   = (const float*)d_in[7];

    float* out  = (float*)d_out;
    float* attn = out + (size_t)8 * 1024 * 1024;

    const size_t E = (size_t)8192 * 1024;
    unsigned short* ws = (unsigned short*)d_ws;
    unsigned short* qh     = ws;                     // bf16 [B][H][L][64]
    unsigned short* kh     = qh + E;                 // bf16 [B][H][L][64]
    unsigned short* vt     = kh + E;                 // bf16 [B][H][64][L]  (transposed)
    unsigned short* xb     = vt + E;                 // bf16 [8192][1024]
    unsigned short* wqkvT  = xb + E;                 // bf16 [3072][1024]
    unsigned short* wprojT = wqkvT + (size_t)3072 * 1024;
    unsigned short* ob     = wprojT + (size_t)1024 * 1024;  // bf16 [8192][1024]
    unsigned short* sb     = (unsigned short*)(void*)qh;    // overlays qh (dead after attn)

    cvt_bf16<<<4096, 256, 0, stream>>>(x, xb, (int)(E / 8));
    tconv_bf16<<<dim3(48, 16), 256, 0, stream>>>(W_qkv, wqkvT, 1024, 3072);
    tconv_bf16<<<dim3(16, 16), 256, 0, stream>>>(W_proj, wprojT, 1024, 1024);

    gemm256_qkv<<<384, 512, 0, stream>>>(xb, wqkvT, b_qkv, qh, kh, vt, 1024);
    attn_kernel<<<dim3(128, 16), 256, 0, stream>>>(qh, kh, vt, attn, ob);
    gemm128_res<<<512, 256, 0, stream>>>(ob, wprojT, b_proj, x, sb, 1024, 64, 1024);
    ln_kernel<<<8192, 256, 0, stream>>>(sb, gamma, beta, out);
}

// Round 17
// 263.670 us; speedup vs baseline: 1.2166x; 1.2166x over previous
//
#include <hip/hip_runtime.h>

typedef __attribute__((ext_vector_type(4))) float f32x4;
typedef __attribute__((ext_vector_type(8))) __bf16 bf16x8;
typedef __attribute__((ext_vector_type(8))) unsigned short ushort8;

static __device__ __forceinline__ unsigned short f2bf(float f) {
    unsigned int u = __float_as_uint(f);
    u += 0x7fffu + ((u >> 16) & 1u);   // round-to-nearest-even
    return (unsigned short)(u >> 16);
}
static __device__ __forceinline__ float bf2f(unsigned short u) {
    return __uint_as_float((unsigned int)u << 16);
}
static __device__ __forceinline__ bf16x8 as_bf(ushort8 v) {
    union { ushort8 u; bf16x8 b; } x; x.u = v; return x.b;
}
// async global->LDS, 16B per lane. LDS dest = wave-uniform base + lane*16.
static __device__ __forceinline__ void gll16(const void* g, void* l) {
    __builtin_amdgcn_global_load_lds(
        (const __attribute__((address_space(1))) void*)g,
        (__attribute__((address_space(3))) void*)l, 16, 0, 0);
}

// ---------------------------------------------------------------------------
// f32 -> bf16 convert (8 elems/thread)
// ---------------------------------------------------------------------------
__global__ void cvt_bf16(const float* __restrict__ in, unsigned short* __restrict__ out,
                         int n8) {
    int i = blockIdx.x * 256 + threadIdx.x;
    if (i >= n8) return;
    const float4* p = (const float4*)(in + (size_t)i * 8);
    float4 a = p[0], b = p[1];
    ushort8 o = { f2bf(a.x), f2bf(a.y), f2bf(a.z), f2bf(a.w),
                  f2bf(b.x), f2bf(b.y), f2bf(b.z), f2bf(b.w) };
    *(ushort8*)(out + (size_t)i * 8) = o;
}

// ---------------------------------------------------------------------------
// transpose + convert: in [K][N] f32 -> out [N][K] bf16. 64x64 tiles.
// ---------------------------------------------------------------------------
__global__ void tconv_bf16(const float* __restrict__ in, unsigned short* __restrict__ out,
                           int K, int N) {
    __shared__ float t[64][65];
    const int tid = threadIdx.x;
    const int n0 = blockIdx.x * 64, k0 = blockIdx.y * 64;
#pragma unroll
    for (int i = 0; i < 4; i++) {
        int idx = tid + 256 * i;
        int r = idx >> 4, c4 = (idx & 15) * 4;
        float4 v = *(const float4*)(in + (size_t)(k0 + r) * N + n0 + c4);
        t[r][c4] = v.x; t[r][c4 + 1] = v.y; t[r][c4 + 2] = v.z; t[r][c4 + 3] = v.w;
    }
    __syncthreads();
#pragma unroll
    for (int i = 0; i < 2; i++) {
        int idx = tid + 256 * i;
        int nl = idx >> 3, k8 = (idx & 7) * 8;
        ushort8 o;
#pragma unroll
        for (int j = 0; j < 8; j++) o[j] = f2bf(t[k8 + j][nl]);
        *(ushort8*)(out + (size_t)(n0 + nl) * K + k0 + k8) = o;
    }
}

// ---------------------------------------------------------------------------
// GEMM1: 256x256 tile, BK=32, 8 waves, counted-vmcnt pipeline (r11, verified).
// ---------------------------------------------------------------------------
__global__ __launch_bounds__(512, 2)
void gemm256_qkv(const unsigned short* __restrict__ A,
                 const unsigned short* __restrict__ BT,
                 const float* __restrict__ bias,
                 unsigned short* __restrict__ qh, unsigned short* __restrict__ kh,
                 unsigned short* __restrict__ vt, int K)
{
    __shared__ char smem[65536];
    const int tid = threadIdx.x;
    const int wid = tid >> 6, lane = tid & 63;
    const int g = lane >> 4, c = lane & 15;
    const int wr = (wid >> 2) * 128;      // M-wave row base (0 / 128)
    const int wc = (wid & 3) * 64;        // N-wave col base (0..192)

    const int nwg = gridDim.x;            // 384 (div by 8)
    const int swz = ((int)blockIdx.x & 7) * (nwg >> 3) + ((int)blockIdx.x >> 3);
    const int bm = (swz & 31) * 256;      // 32 m-tiles
    const int bn = (swz >> 5) * 256;      // 12 n-tiles

    const int sch   = (lane & 7) ^ (lane >> 3);          // swizzled chunk 0..7
    const int srow2 = ((lane >> 3) << 1) + (sch >> 2);   // row offset in 16-row slab
    const int scol  = (sch & 3) * 8;                     // col elems (8 bf16)
    const int fbase = (c >> 1) * 128 + (((((c & 1) << 2) | g) ^ (c >> 1)) * 16);

    f32x4 acc[8][4] = {};

    auto stage = [&](int p, int kt) {
        const int k0 = kt * 32;
        char* bufA = smem + p * 32768;
        char* bufB = bufA + 16384;
#pragma unroll
        for (int half = 0; half < 2; half++) {
            const int PRb = half * 64;
            const int rbase = PRb * 2 + wid * 16 + srow2;
            gll16(A + (size_t)(bm + rbase) * K + k0 + scol,
                  bufA + (PRb + wid * 8) * 128);
            gll16(BT + (size_t)(bn + rbase) * K + k0 + scol,
                  bufB + (PRb + wid * 8) * 128);
        }
    };

    const int NT = K >> 5;    // 32 K-tiles of 32
    stage(0, 0);
    stage(1, 1);

    for (int kt = 0; kt < NT - 1; ++kt) {
        asm volatile("s_waitcnt vmcnt(4)" ::: "memory");   // kt landed; kt+1 in flight
        __builtin_amdgcn_s_barrier();
        const char* bufA = smem + (kt & 1) * 32768;
        const char* bufB = bufA + 16384;
        bf16x8 af[8], bf[4];
#pragma unroll
        for (int mi = 0; mi < 8; mi++)
            af[mi] = as_bf(*(const ushort8*)(bufA + wr * 64 + mi * 1024 + fbase));
#pragma unroll
        for (int ni = 0; ni < 4; ni++)
            bf[ni] = as_bf(*(const ushort8*)(bufB + wc * 64 + ni * 1024 + fbase));
        asm volatile("s_waitcnt lgkmcnt(0)" ::: "memory");
        __builtin_amdgcn_sched_barrier(0);
        __builtin_amdgcn_s_barrier();      // all waves done reading buf[kt&1]
        if (kt + 2 < NT) stage(kt & 1, kt + 2);
        __builtin_amdgcn_sched_barrier(0); // keep stage issue ahead of MFMA
        __builtin_amdgcn_s_setprio(1);
#pragma unroll
        for (int mi = 0; mi < 8; mi++)
#pragma unroll
            for (int ni = 0; ni < 4; ni++)
                acc[mi][ni] = __builtin_amdgcn_mfma_f32_16x16x32_bf16(
                    af[mi], bf[ni], acc[mi][ni], 0, 0, 0);
        __builtin_amdgcn_s_setprio(0);
    }
    {   // final K-tile
        asm volatile("s_waitcnt vmcnt(0)" ::: "memory");
        __builtin_amdgcn_s_barrier();
        const char* bufA = smem + ((NT - 1) & 1) * 32768;
        const char* bufB = bufA + 16384;
        bf16x8 af[8], bf[4];
#pragma unroll
        for (int mi = 0; mi < 8; mi++)
            af[mi] = as_bf(*(const ushort8*)(bufA + wr * 64 + mi * 1024 + fbase));
#pragma unroll
        for (int ni = 0; ni < 4; ni++)
            bf[ni] = as_bf(*(const ushort8*)(bufB + wc * 64 + ni * 1024 + fbase));
        asm volatile("s_waitcnt lgkmcnt(0)" ::: "memory");
        __builtin_amdgcn_sched_barrier(0);
        __builtin_amdgcn_s_barrier();      // frags in regs; LDS free for epilogue
#pragma unroll
        for (int mi = 0; mi < 8; mi++)
#pragma unroll
            for (int ni = 0; ni < 4; ni++)
                acc[mi][ni] = __builtin_amdgcn_mfma_f32_16x16x32_bf16(
                    af[mi], bf[ni], acc[mi][ni], 0, 0, 0);
    }

    // ---- per-wave epilogue ----
    const int n0 = bn + wc;
    const int region = n0 >> 10;
    const int h = (n0 & 1023) >> 6;
    const int b = bm >> 10;
    const int lb = bm & 1023;             // LOCAL sequence base
    const float qscale = (region == 0) ? 0.1803368801f : 1.0f;  // 0.125*log2(e)
    char* W = smem + wid * 8192;   // private 8KB slice per wave

    if (region < 2) {
        unsigned short* dst = (region == 0) ? qh : kh;
#pragma unroll
        for (int hh = 0; hh < 2; hh++) {
#pragma unroll
            for (int mi2 = 0; mi2 < 4; mi2++) {
                int mi = hh * 4 + mi2;
#pragma unroll
                for (int ni = 0; ni < 4; ni++)
#pragma unroll
                    for (int r = 0; r < 4; r++) {
                        int row = mi2 * 16 + g * 4 + r;        // 0..63
                        int col = ni * 16 + c;
                        float v = (acc[mi][ni][r] + bias[n0 + col]) * qscale;
                        *(unsigned short*)(W + row * 128 + ((col * 2) ^ ((row & 7) << 4))) = f2bf(v);
                    }
            }
#pragma unroll
            for (int j = 0; j < 8; j++) {
                int cid = j * 64 + lane;
                int row = cid >> 3, c8 = cid & 7;
                ushort8 v = *(const ushort8*)(W + row * 128 + ((c8 * 16) ^ ((row & 7) << 4)));
                int l = lb + wr + hh * 64 + row;
                *(ushort8*)(dst + ((size_t)((b * 16 + h) * 1024 + l)) * 64 + c8 * 8) = v;
            }
        }
    } else {
#pragma unroll
        for (int hh = 0; hh < 2; hh++) {
#pragma unroll
            for (int mi2 = 0; mi2 < 4; mi2++) {
                int mi = hh * 4 + mi2;
#pragma unroll
                for (int ni = 0; ni < 4; ni++)
#pragma unroll
                    for (int r = 0; r < 4; r++) {
                        int ll = mi2 * 16 + g * 4 + r;         // local l 0..63
                        int d = ni * 16 + c;
                        float v = acc[mi][ni][r] + bias[n0 + d];
                        *(unsigned short*)(W + d * 128 + ((ll * 2) ^ ((d & 7) << 4))) = f2bf(v);
                    }
            }
#pragma unroll
            for (int j = 0; j < 8; j++) {
                int cid = j * 64 + lane;
                int drow = cid >> 3, c8 = cid & 7;
                ushort8 v = *(const ushort8*)(W + drow * 128 + ((c8 * 16) ^ ((drow & 7) << 4)));
                *(ushort8*)(vt + ((size_t)((b * 16 + h) * 64 + drow)) * 1024
                            + (lb + wr + hh * 64) + c8 * 8) = v;
            }
        }
    }
}

// ---------------------------------------------------------------------------
// GEMM2 fused: s[m][n] = bf16( A@W^T + bias + x )  (residual folded in)
// ---------------------------------------------------------------------------
__global__ __launch_bounds__(256, 2)
void gemm128_res(const unsigned short* __restrict__ A,
                 const unsigned short* __restrict__ BT,
                 const float* __restrict__ bias,
                 const float* __restrict__ x,
                 unsigned short* __restrict__ sb, int K, int mtiles, int Ncols)
{
    __shared__ unsigned short smem[2 * 128 * 64];
    unsigned short* As = smem;
    unsigned short* Bs = smem + 128 * 64;

    const int tid = threadIdx.x;
    const int wid = tid >> 6, lane = tid & 63;
    const int g = lane >> 4, c = lane & 15;
    const int wr = (wid >> 1) * 64, wc = (wid & 1) * 64;

    const int nwg = gridDim.x;
    const int swz = ((int)blockIdx.x & 7) * (nwg >> 3) + ((int)blockIdx.x >> 3);
    const int bm = (swz % mtiles) * 128;
    const int bn = (swz / mtiles) * 128;

    const int srow = lane >> 3;
    const int scol8 = ((lane & 7) ^ srow) * 8;
    const size_t arow0 = (size_t)(bm + wid * 8 + srow);
    const size_t brow0 = (size_t)(bn + wid * 8 + srow);

    f32x4 acc[4][4] = {};

    for (int k0 = 0; k0 < K; k0 += 64) {
        __syncthreads();
#pragma unroll
        for (int t = 0; t < 4; t++) {
            gll16(A + (arow0 + t * 32) * K + k0 + scol8,
                  (char*)As + t * 4096 + wid * 1024);
            gll16(BT + (brow0 + t * 32) * K + k0 + scol8,
                  (char*)Bs + t * 4096 + wid * 1024);
        }
        __syncthreads();
#pragma unroll
        for (int ks = 0; ks < 2; ks++) {
            bf16x8 af[4], bfr[4];
#pragma unroll
            for (int mi = 0; mi < 4; mi++) {
                int row = wr + mi * 16 + c;
                int off = row * 128 + ((ks * 64 + g * 16) ^ ((c & 7) << 4));
                af[mi] = as_bf(*(const ushort8*)((const char*)As + off));
            }
#pragma unroll
            for (int ni = 0; ni < 4; ni++) {
                int row = wc + ni * 16 + c;
                int off = row * 128 + ((ks * 64 + g * 16) ^ ((c & 7) << 4));
                bfr[ni] = as_bf(*(const ushort8*)((const char*)Bs + off));
            }
#pragma unroll
            for (int mi = 0; mi < 4; mi++)
#pragma unroll
                for (int ni = 0; ni < 4; ni++)
                    acc[mi][ni] = __builtin_amdgcn_mfma_f32_16x16x32_bf16(
                        af[mi], bfr[ni], acc[mi][ni], 0, 0, 0);
        }
    }

#pragma unroll
    for (int mi = 0; mi < 4; mi++)
#pragma unroll
        for (int ni = 0; ni < 4; ni++)
#pragma unroll
            for (int r = 0; r < 4; r++) {
                int m = bm + wr + mi * 16 + g * 4 + r;
                int n = bn + wc + ni * 16 + c;
                float v = acc[mi][ni][r] + bias[n] + x[(size_t)m * Ncols + n];
                sb[(size_t)m * Ncols + n] = f2bf(v);
            }
}

// ---------------------------------------------------------------------------
// Attention (r14 exact: LJF dispatch, plain coalesced stores — NT regressed).
// ---------------------------------------------------------------------------
__global__ __launch_bounds__(256, 3)
void attn_kernel(const unsigned short* __restrict__ qh,
                 const unsigned short* __restrict__ kh,
                 const unsigned short* __restrict__ vt,
                 float* __restrict__ attn, unsigned short* __restrict__ ob)
{
    __shared__ char smem[49152];

    const int bh = blockIdx.x;       // b*16 + h
    const int qt = 15 - (int)blockIdx.y;   // LJF: big tiles dispatch first
    const int q0 = qt * 64;
    const int ntiles = qt + 1;

    const int tid = threadIdx.x, wid = tid >> 6, lane = tid & 63;
    const int g = lane >> 4, c = lane & 15;

    const size_t baseKV = (size_t)bh * 65536;
    const int qrow = q0 + wid * 16 + c;

    bf16x8 qa[2];
    qa[0] = as_bf(*(const ushort8*)(qh + baseKV + (size_t)qrow * 64 + g * 8));
    qa[1] = as_bf(*(const ushort8*)(qh + baseKV + (size_t)qrow * 64 + 32 + g * 8));

    const int srow = lane >> 3;
    const int scol8 = ((lane & 7) ^ srow) * 8;

    // ---- pass 1: lsum only. stage(kt+1) || compute(kt), 1 barrier/tile.
    float lsum = 0.f;
    {
        int cur = 0;
        const unsigned short* kb0 = kh + baseKV;
        gll16(kb0 + (size_t)(wid * 8 + srow) * 64 + scol8, smem + wid * 1024);
        gll16(kb0 + (size_t)(32 + wid * 8 + srow) * 64 + scol8, smem + 4096 + wid * 1024);
        __syncthreads();
        for (int kt = 0; kt < ntiles; ++kt) {
            if (kt + 1 < ntiles) {
                const unsigned short* kb = kh + baseKV + (size_t)(kt + 1) * 4096;
                char* dst = smem + (cur ^ 1) * 8192;
                gll16(kb + (size_t)(wid * 8 + srow) * 64 + scol8, dst + wid * 1024);
                gll16(kb + (size_t)(32 + wid * 8 + srow) * 64 + scol8, dst + 4096 + wid * 1024);
            }
            const char* Kc = smem + cur * 8192;
            __builtin_amdgcn_s_setprio(1);
#pragma unroll
            for (int a = 0; a < 4; a++) {
                int krow = a * 16 + c;
                f32x4 sa = {0.f, 0.f, 0.f, 0.f};
#pragma unroll
                for (int ks = 0; ks < 2; ks++) {
                    int off = krow * 128 + ((ks * 64 + g * 16) ^ ((c & 7) << 4));
                    bf16x8 kf = as_bf(*(const ushort8*)(Kc + off));
                    sa = __builtin_amdgcn_mfma_f32_16x16x32_bf16(kf, qa[ks], sa, 0, 0, 0);
                }
                int kb4 = kt * 64 + a * 16 + g * 4;
#pragma unroll
                for (int r = 0; r < 4; r++)
                    lsum += (kb4 + r > qrow) ? 0.f : __builtin_amdgcn_exp2f(sa[r]);
            }
            __builtin_amdgcn_s_setprio(0);
            __syncthreads();
            cur ^= 1;
        }
    }
    lsum += __shfl_xor(lsum, 16);
    lsum += __shfl_xor(lsum, 32);
    const float lr = -__log2f(lsum);

    // ---- pass 2: P (normalized at exponent), attn store, O accumulate.
    float* attnB = attn + (size_t)bh * (1024 * 1024) + (size_t)q0 * 1024;
    f32x4 oacc[4] = {};
    {
        int cur = 0;
        const unsigned short* kb0 = kh + baseKV;
        const unsigned short* vb0 = vt + baseKV;
        gll16(kb0 + (size_t)(wid * 8 + srow) * 64 + scol8, smem + wid * 1024);
        gll16(kb0 + (size_t)(32 + wid * 8 + srow) * 64 + scol8, smem + 4096 + wid * 1024);
        gll16(vb0 + (size_t)(wid * 8 + srow) * 1024 + scol8, smem + 16384 + wid * 1024);
        gll16(vb0 + (size_t)(32 + wid * 8 + srow) * 1024 + scol8, smem + 20480 + wid * 1024);
        __syncthreads();

        for (int kt = 0; kt < ntiles; ++kt) {
            if (kt + 1 < ntiles) {
                const unsigned short* kb = kh + baseKV + (size_t)(kt + 1) * 4096;
                const unsigned short* vb = vt + baseKV + (kt + 1) * 64;
                char* kdst = smem + (cur ^ 1) * 8192;
                char* vdst = smem + 16384 + (cur ^ 1) * 8192;
                gll16(kb + (size_t)(wid * 8 + srow) * 64 + scol8, kdst + wid * 1024);
                gll16(kb + (size_t)(32 + wid * 8 + srow) * 64 + scol8, kdst + 4096 + wid * 1024);
                gll16(vb + (size_t)(wid * 8 + srow) * 1024 + scol8, vdst + wid * 1024);
                gll16(vb + (size_t)(32 + wid * 8 + srow) * 1024 + scol8, vdst + 4096 + wid * 1024);
            }
            const char* Kc = smem + cur * 8192;
            const char* Vc = smem + 16384 + cur * 8192;
            char* Pc = smem + 32768 + cur * 8192;
            char* Pw = Pc + wid * 2048;

#pragma unroll
            for (int a = 0; a < 4; a++) {
                int krow = a * 16 + c;
                f32x4 sa = {0.f, 0.f, 0.f, 0.f};
#pragma unroll
                for (int ks = 0; ks < 2; ks++) {
                    int off = krow * 128 + ((ks * 64 + g * 16) ^ ((c & 7) << 4));
                    bf16x8 kf = as_bf(*(const ushort8*)(Kc + off));
                    sa = __builtin_amdgcn_mfma_f32_16x16x32_bf16(kf, qa[ks], sa, 0, 0, 0);
                }
                int kb4 = kt * 64 + a * 16 + g * 4;
                float p0 = __builtin_amdgcn_exp2f((kb4 + 0 > qrow) ? -1e9f : sa[0] + lr);
                float p1 = __builtin_amdgcn_exp2f((kb4 + 1 > qrow) ? -1e9f : sa[1] + lr);
                float p2 = __builtin_amdgcn_exp2f((kb4 + 2 > qrow) ? -1e9f : sa[2] + lr);
                float p3 = __builtin_amdgcn_exp2f((kb4 + 3 > qrow) ? -1e9f : sa[3] + lr);
                uint2 pw;
                asm("v_cvt_pk_bf16_f32 %0, %1, %2" : "=v"(pw.x) : "v"(p0), "v"(p1));
                asm("v_cvt_pk_bf16_f32 %0, %1, %2" : "=v"(pw.y) : "v"(p2), "v"(p3));
                *(uint2*)(Pw + c * 128 + ((a * 32 + g * 8) ^ ((c & 7) << 4))) = pw;
            }

            __builtin_amdgcn_s_setprio(1);
#pragma unroll
            for (int ks = 0; ks < 2; ks++) {
                int aoff = c * 128 + ((ks * 64 + g * 16) ^ ((c & 7) << 4));
                bf16x8 pa = as_bf(*(const ushort8*)(Pw + aoff));
#pragma unroll
                for (int ni = 0; ni < 4; ni++) {
                    int d = ni * 16 + c;
                    int voff = d * 128 + ((ks * 64 + g * 16) ^ ((d & 7) << 4));
                    bf16x8 vf = as_bf(*(const ushort8*)(Vc + voff));
                    oacc[ni] = __builtin_amdgcn_mfma_f32_16x16x32_bf16(pa, vf, oacc[ni], 0, 0, 0);
                }
            }
            __builtin_amdgcn_s_setprio(0);
            __syncthreads();

#pragma unroll
            for (int i = 0; i < 2; i++) {
                int idx = tid + 256 * i;
                int row = idx >> 3, c16 = idx & 7;
                int off = (row >> 4) * 2048 + (row & 15) * 128 + ((c16 * 16) ^ ((row & 7) << 4));
                ushort8 v = *(const ushort8*)(Pc + off);
                float4 f0 = { bf2f(v[0]), bf2f(v[1]), bf2f(v[2]), bf2f(v[3]) };
                float4 f1 = { bf2f(v[4]), bf2f(v[5]), bf2f(v[6]), bf2f(v[7]) };
                float* dp = attnB + (size_t)row * 1024 + kt * 64 + c16 * 8;
                *(float4*)dp = f0;
                *(float4*)(dp + 4) = f1;
            }
            cur ^= 1;
        }
    }

    // zero the strictly-upper k-tiles (end burst)
    {
        float4 z = {0.f, 0.f, 0.f, 0.f};
        for (int kt = ntiles; kt < 16; ++kt) {
#pragma unroll
            for (int i = 0; i < 4; i++) {
                int idx = tid + 256 * i;
                int row = idx >> 4, c4 = (idx & 15) << 2;
                *(float4*)(attnB + (size_t)row * 1024 + kt * 64 + c4) = z;
            }
        }
    }

    // O store via LDS roundtrip -> bf16
    __syncthreads();
#pragma unroll
    for (int ni = 0; ni < 4; ni++)
#pragma unroll
        for (int r = 0; r < 4; r++) {
            int row = wid * 16 + g * 4 + r;
            int d = ni * 16 + c;
            int off = row * 128 + ((d * 2) ^ ((row & 7) << 4));
            *(unsigned short*)(smem + off) = f2bf(oacc[ni][r]);
        }
    __syncthreads();
    {
        const int b = bh >> 4, h = bh & 15;
#pragma unroll
        for (int i = 0; i < 2; i++) {
            int idx = tid + 256 * i;
            int row = idx >> 3, c8 = idx & 7;
            int off = row * 128 + ((c8 * 16) ^ ((row & 7) << 4));
            ushort8 v = *(const ushort8*)(smem + off);
            *(ushort8*)(ob + ((size_t)(b * 1024 + q0 + row)) * 1024 + h * 64 + c8 * 8) = v;
        }
    }
}

// ---------------------------------------------------------------------------
// LayerNorm(s) -> out   (s = y + x already fused, bf16)
// ---------------------------------------------------------------------------
__global__ __launch_bounds__(256, 2)
void ln_kernel(const unsigned short* __restrict__ sb,
               const float* __restrict__ gamma, const float* __restrict__ beta,
               float* __restrict__ out)
{
    const int m = blockIdx.x;
    const int tid = threadIdx.x;
    const int wid = tid >> 6, lane = tid & 63;
    ushort4 u = *(const ushort4*)(sb + (size_t)m * 1024 + tid * 4);
    float4 v = { bf2f(u.x), bf2f(u.y), bf2f(u.z), bf2f(u.w) };
    float s1 = v.x + v.y + v.z + v.w;
    float s2 = v.x * v.x + v.y * v.y + v.z * v.z + v.w * v.w;
#pragma unroll
    for (int d = 1; d < 64; d <<= 1) {
        s1 += __shfl_xor(s1, d);
        s2 += __shfl_xor(s2, d);
    }
    __shared__ float red1[4], red2[4];
    if (lane == 0) { red1[wid] = s1; red2[wid] = s2; }
    __syncthreads();
    float t1 = red1[0] + red1[1] + red1[2] + red1[3];
    float t2 = red2[0] + red2[1] + red2[2] + red2[3];
    float mean = t1 * (1.f / 1024.f);
    float var = t2 * (1.f / 1024.f) - mean * mean;
    float rstd = rsqrtf(var + 1e-5f);
    float4 g4 = *(const float4*)(gamma + tid * 4);
    float4 b4 = *(const float4*)(beta + tid * 4);
    float4 o;
    o.x = g4.x * (v.x - mean) * rstd + b4.x;
    o.y = g4.y * (v.y - mean) * rstd + b4.y;
    o.z = g4.z * (v.z - mean) * rstd + b4.z;
    o.w = g4.w * (v.w - mean) * rstd + b4.w;
    *(float4*)(out + (size_t)m * 1024 + tid * 4) = o;
}

// ---------------------------------------------------------------------------
extern "C" void kernel_launch(void* const* d_in, const int* in_sizes, int n_in,
                              void* d_out, int out_size, void* d_ws, size_t ws_size,
                              hipStream_t stream)
{
    const float* x      = (const float*)d_in[0];
    // d_in[1] = mask — causal, implemented analytically
    const float* W_qkv  = (const float*)d_in[2];
    const float* b_qkv  = (const float*)d_in[3];
    const float* W_proj = (const float*)d_in[4];
    const float* b_proj = (const float*)d_in[5];
    const float* gamma  = (const float*)d_in[6];
    const float* beta   = (const float*)d_in[7];

    float* out  = (float*)d_out;
    float* attn = out + (size_t)8 * 1024 * 1024;

    const size_t E = (size_t)8192 * 1024;
    unsigned short* ws = (unsigned short*)d_ws;
    unsigned short* qh     = ws;                     // bf16 [B][H][L][64]
    unsigned short* kh     = qh + E;                 // bf16 [B][H][L][64]
    unsigned short* vt     = kh + E;                 // bf16 [B][H][64][L]  (transposed)
    unsigned short* xb     = vt + E;                 // bf16 [8192][1024]
    unsigned short* wqkvT  = xb + E;                 // bf16 [3072][1024]
    unsigned short* wprojT = wqkvT + (size_t)3072 * 1024;
    unsigned short* ob     = wprojT + (size_t)1024 * 1024;  // bf16 [8192][1024]
    unsigned short* sb     = (unsigned short*)(void*)qh;    // overlays qh (dead after attn)

    cvt_bf16<<<4096, 256, 0, stream>>>(x, xb, (int)(E / 8));
    tconv_bf16<<<dim3(48, 16), 256, 0, stream>>>(W_qkv, wqkvT, 1024, 3072);
    tconv_bf16<<<dim3(16, 16), 256, 0, stream>>>(W_proj, wprojT, 1024, 1024);

    gemm256_qkv<<<384, 512, 0, stream>>>(xb, wqkvT, b_qkv, qh, kh, vt, 1024);
    attn_kernel<<<dim3(128, 16), 256, 0, stream>>>(qh, kh, vt, attn, ob);
    gemm128_res<<<512, 256, 0, stream>>>(ob, wprojT, b_proj, x, sb, 1024, 64, 1024);
    ln_kernel<<<8192, 256, 0, stream>>>(sb, gamma, beta, out);
}